// Round 1
// baseline (1814.850 us; speedup 1.0000x reference)
//
#include <hip/hip_runtime.h>

#define HN 10
#define KN 8

__device__ __forceinline__ float fast_sigmoid(float x) {
    return __builtin_amdgcn_rcpf(1.0f + __expf(-x));
}
__device__ __forceinline__ float fast_tanh(float x) {
    return 2.0f * __builtin_amdgcn_rcpf(1.0f + __expf(-2.0f * x)) - 1.0f;
}

__device__ __forceinline__ float dot10(const float* __restrict__ w, const float* __restrict__ x) {
    float s = 0.0f;
#pragma unroll
    for (int t = 0; t < 10; ++t) s = __builtin_fmaf(w[t], x[t], s);
    return s;
}

__device__ __forceinline__ void store10(float* __restrict__ dst, const float* __restrict__ h) {
    float2* d = reinterpret_cast<float2*>(dst);
    d[0] = make_float2(h[0], h[1]);
    d[1] = make_float2(h[2], h[3]);
    d[2] = make_float2(h[4], h[5]);
    d[3] = make_float2(h[6], h[7]);
    d[4] = make_float2(h[8], h[9]);
}

__global__ __launch_bounds__(256, 4) void Piston_PolicyHelper_gru_kernel(
    const float* __restrict__ policy,   // [B,10]
    const float* __restrict__ neigh,    // [B,8,10]
    const float* __restrict__ w_ih,     // [30,10]
    const float* __restrict__ w_hh,     // [30,10]
    const float* __restrict__ b_ih,     // [30]
    const float* __restrict__ b_hh,     // [30]
    float* __restrict__ out,            // [B*10] final, then [B*90] temp
    int B)
{
    // ---- stage weights to LDS, rows padded 10 -> 12 floats (48B, 16B-aligned) ----
    __shared__ __align__(16) float sWI[30 * 12];
    __shared__ __align__(16) float sWH[30 * 12];
    __shared__ float sBI[30];
    __shared__ float sBH[30];

    const int tid = threadIdx.x;
    for (int i = tid; i < 300; i += 256) {
        int r = i / 10;
        int c = i - r * 10;
        sWI[r * 12 + c] = w_ih[i];
        sWH[r * 12 + c] = w_hh[i];
    }
    if (tid < 30) { sBI[tid] = b_ih[tid]; sBH[tid] = b_hh[tid]; }
    __syncthreads();

    const int b = blockIdx.x * 256 + tid;
    if (b >= B) return;

    // ---- load initial h (policy_dist row) ----
    float h[10];
    {
        const float2* p = reinterpret_cast<const float2*>(policy + (size_t)b * 10);
#pragma unroll
        for (int i = 0; i < 5; ++i) {
            float2 v = p[i];
            h[2 * i] = v.x;
            h[2 * i + 1] = v.y;
        }
    }

    float* finp = out + (size_t)b * 10;
    float* temp = out + (size_t)B * 10 + (size_t)b * 90;

    // temp[:,0,:] = initial h
    store10(temp, h);

    const float4* nb4 = reinterpret_cast<const float4*>(neigh + (size_t)b * 80);

#pragma unroll 1
    for (int kk = 0; kk < 4; ++kk) {
        // load 2 neighbor steps (20 floats) as 5x float4, 16B-aligned
        float x[20];
#pragma unroll
        for (int i = 0; i < 5; ++i) {
            float4 v = nb4[kk * 5 + i];
            x[4 * i + 0] = v.x;
            x[4 * i + 1] = v.y;
            x[4 * i + 2] = v.z;
            x[4 * i + 3] = v.w;
        }
#pragma unroll
        for (int s = 0; s < 2; ++s) {
            const float* xs = x + s * 10;
            float hn[10];
#pragma unroll
            for (int j = 0; j < 10; ++j) {
                float ir = sBI[j]      + dot10(sWI + j * 12,        xs);
                float iz = sBI[10 + j] + dot10(sWI + (10 + j) * 12, xs);
                float in = sBI[20 + j] + dot10(sWI + (20 + j) * 12, xs);
                float hr = sBH[j]      + dot10(sWH + j * 12,        h);
                float hz = sBH[10 + j] + dot10(sWH + (10 + j) * 12, h);
                float hg = sBH[20 + j] + dot10(sWH + (20 + j) * 12, h);
                float r = fast_sigmoid(ir + hr);
                float z = fast_sigmoid(iz + hz);
                float n = fast_tanh(in + r * hg);
                hn[j] = (1.0f - z) * n + z * h[j];
            }
#pragma unroll
            for (int j = 0; j < 10; ++j) h[j] = hn[j];
            store10(temp + (size_t)(kk * 2 + s + 1) * 10, h);
        }
    }

    store10(finp, h);
}

extern "C" void kernel_launch(void* const* d_in, const int* in_sizes, int n_in,
                              void* d_out, int out_size, void* d_ws, size_t ws_size,
                              hipStream_t stream) {
    const float* policy = (const float*)d_in[0];
    const float* neigh  = (const float*)d_in[1];
    const float* w_ih   = (const float*)d_in[2];
    const float* w_hh   = (const float*)d_in[3];
    const float* b_ih   = (const float*)d_in[4];
    const float* b_hh   = (const float*)d_in[5];
    float* out = (float*)d_out;

    const int B = in_sizes[0] / HN;   // 262144
    const int grid = (B + 255) / 256;

    Piston_PolicyHelper_gru_kernel<<<grid, 256, 0, stream>>>(
        policy, neigh, w_ih, w_hh, b_ih, b_hh, out, B);
}

// Round 6
// 1445.804 us; speedup vs baseline: 1.2553x; 1.2553x over previous
//
#include <hip/hip_runtime.h>

#define HN 10
#define KN 8

__device__ __forceinline__ float fast_sigmoid(float x) {
    return __builtin_amdgcn_rcpf(1.0f + __expf(-x));
}
__device__ __forceinline__ float fast_tanh(float x) {
    return 2.0f * __builtin_amdgcn_rcpf(1.0f + __expf(-2.0f * x)) - 1.0f;
}

__device__ __forceinline__ float dot10(const float* __restrict__ w, const float* __restrict__ x) {
    float s = 0.0f;
#pragma unroll
    for (int t = 0; t < 10; ++t) s = __builtin_fmaf(w[t], x[t], s);
    return s;
}

__global__ __launch_bounds__(256, 3) void Piston_PolicyHelper_gru_kernel(
    const float* __restrict__ policy,   // [B,10]
    const float* __restrict__ neigh,    // [B,8,10]
    const float* __restrict__ w_ih,     // [30,10]
    const float* __restrict__ w_hh,     // [30,10]
    const float* __restrict__ b_ih,     // [30]
    const float* __restrict__ b_hh,     // [30]
    float* __restrict__ out,            // [B*10] final, then [B*90] temp
    int B)
{
    // ---- weights in LDS, rows padded 10 -> 12 floats ----
    __shared__ __align__(16) float sWI[30 * 12];
    __shared__ __align__(16) float sWH[30 * 12];
    __shared__ float sBI[30];
    __shared__ float sBH[30];
    // ---- output-staging buffer: 64 rows x 90 floats, stride 91 (coprime with 32 banks) ----
    __shared__ float sBuf[64 * 91];

    const int tid = threadIdx.x;
    for (int i = tid; i < 300; i += 256) {
        int r = i / 10;
        int c = i - r * 10;
        sWI[r * 12 + c] = w_ih[i];
        sWH[r * 12 + c] = w_hh[i];
    }
    if (tid < 30) { sBI[tid] = b_ih[tid]; sBH[tid] = b_hh[tid]; }
    __syncthreads();

    const int b = blockIdx.x * 256 + tid;   // B == 262144 is divisible by 256

    // ---- hist[0..10) = initial h (policy row); hist[(s+1)*10..] = h after step s ----
    float hist[90];
    {
        const float2* p = reinterpret_cast<const float2*>(policy + (size_t)b * 10);
#pragma unroll
        for (int i = 0; i < 5; ++i) {
            float2 v = p[i];
            hist[2 * i]     = v.x;
            hist[2 * i + 1] = v.y;
        }
    }

    const float4* nb4 = reinterpret_cast<const float4*>(neigh + (size_t)b * 80);

#pragma unroll
    for (int kk = 0; kk < 4; ++kk) {
        // 2 neighbor steps (20 floats) as 5x float4
        float x[20];
#pragma unroll
        for (int i = 0; i < 5; ++i) {
            float4 v = nb4[kk * 5 + i];
            x[4 * i + 0] = v.x;
            x[4 * i + 1] = v.y;
            x[4 * i + 2] = v.z;
            x[4 * i + 3] = v.w;
        }
#pragma unroll
        for (int s = 0; s < 2; ++s) {
            const int step = kk * 2 + s;
            const float* xs = x + s * 10;
            const float* hp = hist + step * 10;        // h_in
            float*       hq = hist + (step + 1) * 10;  // h_out
#pragma unroll
            for (int j = 0; j < 10; ++j) {
                float ir = sBI[j]      + dot10(sWI + j * 12,        xs);
                float iz = sBI[10 + j] + dot10(sWI + (10 + j) * 12, xs);
                float in = sBI[20 + j] + dot10(sWI + (20 + j) * 12, xs);
                float hr = sBH[j]      + dot10(sWH + j * 12,        hp);
                float hz = sBH[10 + j] + dot10(sWH + (10 + j) * 12, hp);
                float hg = sBH[20 + j] + dot10(sWH + (20 + j) * 12, hp);
                float r = fast_sigmoid(ir + hr);
                float z = fast_sigmoid(iz + hz);
                float n = fast_tanh(in + r * hg);
                hq[j] = (1.0f - z) * n + z * hp[j];
            }
        }
    }

    // ---- final h: 5 adjacent float2 stores per lane ----
    {
        float2* d = reinterpret_cast<float2*>(out + (size_t)b * 10);
#pragma unroll
        for (int i = 0; i < 5; ++i)
            d[i] = make_float2(hist[80 + 2 * i], hist[80 + 2 * i + 1]);
    }

    // ---- temp history: LDS transpose flush, 4 chunks of 64 rows ----
    const int chunk = tid >> 6;
    const int lane  = tid & 63;
    float* tempBase = out + (size_t)B * 10;

    for (int c = 0; c < 4; ++c) {
        __syncthreads();
        if (chunk == c) {
#pragma unroll
            for (int j = 0; j < 90; ++j) sBuf[lane * 91 + j] = hist[j];
        }
        __syncthreads();
        // 64 rows x 90 floats = 5760 floats = 2880 float2, contiguous in global
        float2* dst = reinterpret_cast<float2*>(
            tempBase + ((size_t)blockIdx.x * 256 + c * 64) * 90);
        for (int i = tid; i < 2880; i += 256) {
            int e   = 2 * i;
            int row = e / 90;
            int col = e - row * 90;
            int w   = row * 91 + col;
            dst[i] = make_float2(sBuf[w], sBuf[w + 1]);
        }
    }
}

extern "C" void kernel_launch(void* const* d_in, const int* in_sizes, int n_in,
                              void* d_out, int out_size, void* d_ws, size_t ws_size,
                              hipStream_t stream) {
    const float* policy = (const float*)d_in[0];
    const float* neigh  = (const float*)d_in[1];
    const float* w_ih   = (const float*)d_in[2];
    const float* w_hh   = (const float*)d_in[3];
    const float* b_ih   = (const float*)d_in[4];
    const float* b_hh   = (const float*)d_in[5];
    float* out = (float*)d_out;

    const int B = in_sizes[0] / HN;   // 262144
    const int grid = (B + 255) / 256;

    Piston_PolicyHelper_gru_kernel<<<grid, 256, 0, stream>>>(
        policy, neigh, w_ih, w_hh, b_ih, b_hh, out, B);
}

// Round 9
// 1242.694 us; speedup vs baseline: 1.4604x; 1.1634x over previous
//
#include <hip/hip_runtime.h>

#define HN 10

__device__ __forceinline__ float fast_sigmoid(float x) {
    return __builtin_amdgcn_rcpf(1.0f + __expf(-x));
}
__device__ __forceinline__ float fast_tanh(float x) {
    return 2.0f * __builtin_amdgcn_rcpf(1.0f + __expf(-2.0f * x)) - 1.0f;
}

__device__ __forceinline__ float dot10(const float* __restrict__ w, const float* __restrict__ x) {
    float s = 0.0f;
#pragma unroll
    for (int t = 0; t < 10; ++t) s = __builtin_fmaf(w[t], x[t], s);
    return s;
}

// ============ Kernel 1: GRU recurrence, history streamed transposed to ws ============
// ws layout: [90][B]  row m = step_idx*10 + j  (step_idx 0 = initial h), value = h[j] for batch b.
// Every store: lane->consecutive b => 256B contiguous, 256B-aligned, full lines, no RMW.
__global__ __launch_bounds__(256, 4) void Piston_PolicyHelper_gru_fwd(
    const float* __restrict__ policy,   // [B,10]
    const float* __restrict__ neigh,    // [B,8,10]
    const float* __restrict__ w_ih,     // [30,10]
    const float* __restrict__ w_hh,     // [30,10]
    const float* __restrict__ b_ih,     // [30]
    const float* __restrict__ b_hh,     // [30]
    float* __restrict__ ws,             // [90,B]
    int B)
{
    __shared__ __align__(16) float sWI[30 * 12];
    __shared__ __align__(16) float sWH[30 * 12];
    __shared__ float sBI[30];
    __shared__ float sBH[30];

    const int tid = threadIdx.x;
    for (int i = tid; i < 300; i += 256) {
        int r = i / 10;
        int c = i - r * 10;
        sWI[r * 12 + c] = w_ih[i];
        sWH[r * 12 + c] = w_hh[i];
    }
    if (tid < 30) { sBI[tid] = b_ih[tid]; sBH[tid] = b_hh[tid]; }
    __syncthreads();

    const int b = blockIdx.x * 256 + tid;

    float h[10];
    {
        const float2* p = reinterpret_cast<const float2*>(policy + (size_t)b * 10);
#pragma unroll
        for (int i = 0; i < 5; ++i) {
            float2 v = p[i];
            h[2 * i]     = v.x;
            h[2 * i + 1] = v.y;
        }
    }

    // initial h -> ws rows 0..9
#pragma unroll
    for (int j = 0; j < 10; ++j) ws[(size_t)j * B + b] = h[j];

    const float4* nb4 = reinterpret_cast<const float4*>(neigh + (size_t)b * 80);

    // software prefetch one kk-chunk ahead
    float4 pre[5];
#pragma unroll
    for (int i = 0; i < 5; ++i) pre[i] = nb4[i];

#pragma unroll 1
    for (int kk = 0; kk < 4; ++kk) {
        float x[20];
#pragma unroll
        for (int i = 0; i < 5; ++i) {
            float4 v = pre[i];
            x[4 * i + 0] = v.x;
            x[4 * i + 1] = v.y;
            x[4 * i + 2] = v.z;
            x[4 * i + 3] = v.w;
        }
        if (kk < 3) {
#pragma unroll
            for (int i = 0; i < 5; ++i) pre[i] = nb4[(kk + 1) * 5 + i];
        }
#pragma unroll
        for (int s = 0; s < 2; ++s) {
            const float* xs = x + s * 10;
            float hn[10];
#pragma unroll
            for (int j = 0; j < 10; ++j) {
                float ir = sBI[j]      + dot10(sWI + j * 12,        xs);
                float iz = sBI[10 + j] + dot10(sWI + (10 + j) * 12, xs);
                float in = sBI[20 + j] + dot10(sWI + (20 + j) * 12, xs);
                float hr = sBH[j]      + dot10(sWH + j * 12,        h);
                float hz = sBH[10 + j] + dot10(sWH + (10 + j) * 12, h);
                float hg = sBH[20 + j] + dot10(sWH + (20 + j) * 12, h);
                float r = fast_sigmoid(ir + hr);
                float z = fast_sigmoid(iz + hz);
                float n = fast_tanh(in + r * hg);
                hn[j] = (1.0f - z) * n + z * h[j];
            }
#pragma unroll
            for (int j = 0; j < 10; ++j) h[j] = hn[j];
            // step (kk*2+s) -> ws rows (kk*2+s+1)*10 + j   (runtime row in ADDRESS only)
            const size_t rowBase = (size_t)((kk * 2 + s + 1) * 10) * B + b;
#pragma unroll
            for (int j = 0; j < 10; ++j) ws[rowBase + (size_t)j * B] = h[j];
        }
    }
}

// ============ Kernel 2: transpose ws [90][B] -> out {[B,10] final, [B,9,10] temp} ============
__global__ __launch_bounds__(256, 4) void Piston_PolicyHelper_gru_tr(
    const float* __restrict__ ws,
    float* __restrict__ out,
    int B)
{
    __shared__ float sT[90 * 65];   // [row 90][col 64 +1 pad]; 65%32==1 -> conflict-free

    const int tid = threadIdx.x;
    const int bbase = blockIdx.x * 64;

    // stage: coalesced reads along b
    for (int i = tid; i < 5760; i += 256) {
        int row = i >> 6;
        int col = i & 63;
        sT[row * 65 + col] = ws[(size_t)row * B + bbase + col];
    }
    __syncthreads();

    // temp history: out[B*10 + (bbase+r)*90 + c] = sT[c][r]
    float* temp = out + (size_t)B * 10;
    for (int i = tid; i < 5760; i += 256) {
        int r = i / 90;
        int c = i - r * 90;
        temp[(size_t)(bbase + r) * 90 + c] = sT[c * 65 + r];
    }
    // final h: rows 80..89
    for (int i = tid; i < 640; i += 256) {
        int r = i / 10;
        int c = i - r * 10;
        out[(size_t)(bbase + r) * 10 + c] = sT[(80 + c) * 65 + r];
    }
}

// ============ Fallback (verified R1 kernel) if ws too small ============
__global__ __launch_bounds__(256, 3) void Piston_PolicyHelper_gru_mono(
    const float* __restrict__ policy, const float* __restrict__ neigh,
    const float* __restrict__ w_ih, const float* __restrict__ w_hh,
    const float* __restrict__ b_ih, const float* __restrict__ b_hh,
    float* __restrict__ out, int B)
{
    __shared__ __align__(16) float sWI[30 * 12];
    __shared__ __align__(16) float sWH[30 * 12];
    __shared__ float sBI[30];
    __shared__ float sBH[30];
    __shared__ float sBuf[64 * 91];

    const int tid = threadIdx.x;
    for (int i = tid; i < 300; i += 256) {
        int r = i / 10;
        int c = i - r * 10;
        sWI[r * 12 + c] = w_ih[i];
        sWH[r * 12 + c] = w_hh[i];
    }
    if (tid < 30) { sBI[tid] = b_ih[tid]; sBH[tid] = b_hh[tid]; }
    __syncthreads();

    const int b = blockIdx.x * 256 + tid;
    float hist[90];
    {
        const float2* p = reinterpret_cast<const float2*>(policy + (size_t)b * 10);
#pragma unroll
        for (int i = 0; i < 5; ++i) {
            float2 v = p[i];
            hist[2 * i] = v.x;
            hist[2 * i + 1] = v.y;
        }
    }
    const float4* nb4 = reinterpret_cast<const float4*>(neigh + (size_t)b * 80);
#pragma unroll
    for (int kk = 0; kk < 4; ++kk) {
        float x[20];
#pragma unroll
        for (int i = 0; i < 5; ++i) {
            float4 v = nb4[kk * 5 + i];
            x[4 * i + 0] = v.x; x[4 * i + 1] = v.y; x[4 * i + 2] = v.z; x[4 * i + 3] = v.w;
        }
#pragma unroll
        for (int s = 0; s < 2; ++s) {
            const int step = kk * 2 + s;
            const float* xs = x + s * 10;
            const float* hp = hist + step * 10;
            float*       hq = hist + (step + 1) * 10;
#pragma unroll
            for (int j = 0; j < 10; ++j) {
                float ir = sBI[j]      + dot10(sWI + j * 12,        xs);
                float iz = sBI[10 + j] + dot10(sWI + (10 + j) * 12, xs);
                float in = sBI[20 + j] + dot10(sWI + (20 + j) * 12, xs);
                float hr = sBH[j]      + dot10(sWH + j * 12,        hp);
                float hz = sBH[10 + j] + dot10(sWH + (10 + j) * 12, hp);
                float hg = sBH[20 + j] + dot10(sWH + (20 + j) * 12, hp);
                float r = fast_sigmoid(ir + hr);
                float z = fast_sigmoid(iz + hz);
                float n = fast_tanh(in + r * hg);
                hq[j] = (1.0f - z) * n + z * hp[j];
            }
        }
    }
    {
        float2* d = reinterpret_cast<float2*>(out + (size_t)b * 10);
#pragma unroll
        for (int i = 0; i < 5; ++i)
            d[i] = make_float2(hist[80 + 2 * i], hist[80 + 2 * i + 1]);
    }
    const int chunk = tid >> 6;
    const int lane  = tid & 63;
    float* tempBase = out + (size_t)B * 10;
    for (int c = 0; c < 4; ++c) {
        __syncthreads();
        if (chunk == c) {
#pragma unroll
            for (int j = 0; j < 90; ++j) sBuf[lane * 91 + j] = hist[j];
        }
        __syncthreads();
        float2* dst = reinterpret_cast<float2*>(
            tempBase + ((size_t)blockIdx.x * 256 + c * 64) * 90);
        for (int i = tid; i < 2880; i += 256) {
            int e = 2 * i;
            int row = e / 90;
            int col = e - row * 90;
            int w = row * 91 + col;
            dst[i] = make_float2(sBuf[w], sBuf[w + 1]);
        }
    }
}

extern "C" void kernel_launch(void* const* d_in, const int* in_sizes, int n_in,
                              void* d_out, int out_size, void* d_ws, size_t ws_size,
                              hipStream_t stream) {
    const float* policy = (const float*)d_in[0];
    const float* neigh  = (const float*)d_in[1];
    const float* w_ih   = (const float*)d_in[2];
    const float* w_hh   = (const float*)d_in[3];
    const float* b_ih   = (const float*)d_in[4];
    const float* b_hh   = (const float*)d_in[5];
    float* out = (float*)d_out;

    const int B = in_sizes[0] / HN;   // 262144
    const size_t wsNeed = (size_t)B * 90 * sizeof(float);

    if (ws_size >= wsNeed) {
        float* ws = (float*)d_ws;
        Piston_PolicyHelper_gru_fwd<<<(B + 255) / 256, 256, 0, stream>>>(
            policy, neigh, w_ih, w_hh, b_ih, b_hh, ws, B);
        Piston_PolicyHelper_gru_tr<<<B / 64, 256, 0, stream>>>(ws, out, B);
    } else {
        Piston_PolicyHelper_gru_mono<<<(B + 255) / 256, 256, 0, stream>>>(
            policy, neigh, w_ih, w_hh, b_ih, b_hh, out, B);
    }
}